// Round 2
// baseline (45.977 us; speedup 1.0000x reference)
//
#include <hip/hip_runtime.h>

// SineSynth: B=4, S=1000 sines, F=256 frames, 32x linear upsample -> T=8192.
// out[b][t] = sum_s amp_up[b,s,t] * sin( cumsum(freq_up*2pi/FS)[t] + init[b,s] )
//
// Closed-form phase (in REVOLUTIONS, so v_fract feeds v_sin_f32 directly):
//   t = 32k+16+j (k in [0,255], j in [0,32)):
//   base(k)   = 16*(C[k]+C[k+1])/FS + init/(2pi),  C[k]=sum_{m<k} f[m]
//   phase(j)  = base + c1*(j+1) + c2*(j+1)^2,  c1=f[k]/FS, c2=(f[k+1]-f[k])/(64 FS)
//   amp(j)    = a[k] + (a[k+1]-a[k])*(j+0.5)/32
//   head t<16:  phase = (t+1)*f[0]/FS + init/(2pi), amp = a[0]
//   tail k=255: f[256]:=f[255] (c2=0), amp = a[255]

#define FS_D 44100.0
#define S_TOTAL 1000
#define FRAMES 256
#define T_OUT 8192
#define BATCH 4

template <int CHT, int NCT, bool ATOMIC>
__global__ __launch_bounds__(256) void synth_partial(
    const float* __restrict__ freq, const float* __restrict__ amp,
    const float* __restrict__ initp, float* __restrict__ dst)
{
  __shared__ float base_lds[CHT][FRAMES];
  __shared__ float head_lds[CHT];

  const int b     = blockIdx.x / NCT;
  const int chunk = blockIdx.x % NCT;
  const int s0    = chunk * CHT;
  const int tid   = threadIdx.x;
  const int lane  = tid & 63;
  const int wave  = tid >> 6;

  const double inv2pi = 0.15915494309189535;
  const double k16    = 16.0 / FS_D;

  // ---- Phase 1: per-row exclusive scan (double) -> segment base fracs ----
  for (int r = wave; r < CHT; r += 4) {
    const int s = s0 + r;   // always < S_TOTAL (CHT*NCT == S_TOTAL)
    const long long roff = (long long)(b * S_TOTAL + s) * FRAMES;
    const float4 fv = reinterpret_cast<const float4*>(freq + roff)[lane];
    const double f0 = fv.x, f1 = fv.y, f2 = fv.z, f3 = fv.w;
    const double tot = f0 + f1 + f2 + f3;
    double incl = tot;
    #pragma unroll
    for (int off = 1; off < 64; off <<= 1) {
      double v = __shfl_up(incl, (unsigned)off, 64);
      if (lane >= off) incl += v;
    }
    double C = incl - tot;  // exclusive prefix of frames at 4*lane
    const double initrev = (double)initp[b * S_TOTAL + s] * inv2pi;
    if (lane == 0) head_lds[r] = (float)(initrev - floor(initrev));
    const double fk[4] = {f0, f1, f2, f3};
    #pragma unroll
    for (int i = 0; i < 4; ++i) {
      const double basev = k16 * (2.0 * C + fk[i]) + initrev;
      base_lds[r][4 * lane + i] = (float)(basev - floor(basev));
      C += fk[i];
    }
  }
  __syncthreads();

  // ---- Phase 2: thread k owns output segment k (32 samples) ----
  const int k = tid;                 // 0..255
  float acc[32];
  #pragma unroll
  for (int j = 0; j < 32; ++j) acc[j] = 0.f;

  const float invfs = (float)(1.0 / FS_D);

  // Load ALL coefficients up front (fully unrolled -> 4*CHT loads in flight)
  float fk_r[CHT], fk1_r[CHT], ak_r[CHT], ak1_r[CHT], base_r[CHT];
  const int kp1 = (k < FRAMES - 1) ? (k + 1) : k;
  #pragma unroll
  for (int r = 0; r < CHT; ++r) {
    const long long roff = (long long)(b * S_TOTAL + s0 + r) * FRAMES;
    fk_r[r]  = freq[roff + k];
    fk1_r[r] = freq[roff + kp1];
    ak_r[r]  = amp[roff + k];
    ak1_r[r] = amp[roff + kp1];
    base_r[r] = base_lds[r][k];
  }

  if (k < FRAMES - 1) {
    #pragma unroll
    for (int r = 0; r < CHT; ++r) {
      const float c1 = fk_r[r] * invfs;
      const float c2 = (fk1_r[r] - fk_r[r]) * (invfs * (1.0f / 64.0f));
      const float d1 = (ak1_r[r] - ak_r[r]) * (1.0f / 32.0f);
      const float a0 = ak_r[r];
      const float bs = base_r[r];
      #pragma unroll
      for (int j = 0; j < 32; ++j) {
        const float u  = (float)(j + 1);
        const float p  = fmaf(u, fmaf(c2, u, c1), bs);
        const float am = fmaf((float)j + 0.5f, d1, a0);
        acc[j] = fmaf(am, __builtin_amdgcn_sinf(__builtin_amdgcn_fractf(p)), acc[j]);
      }
    }
  } else {
    #pragma unroll
    for (int r = 0; r < CHT; ++r) {
      const long long roff = (long long)(b * S_TOTAL + s0 + r) * FRAMES;
      const float c1 = fk_r[r] * invfs;     // tail: c2 = 0, d1 = 0
      const float a0 = ak_r[r];
      const float bs = base_r[r];
      #pragma unroll
      for (int j = 0; j < 16; ++j) {        // t = 8176..8191
        const float p = fmaf((float)(j + 1), c1, bs);
        acc[j] = fmaf(a0, __builtin_amdgcn_sinf(__builtin_amdgcn_fractf(p)), acc[j]);
      }
      const float f0v = freq[roff];
      const float a0v = amp[roff];
      const float c1h = f0v * invfs;
      const float bh  = head_lds[r];
      #pragma unroll
      for (int j = 0; j < 16; ++j) {        // t = 0..15
        const float p = fmaf((float)(j + 1), c1h, bh);
        acc[16 + j] = fmaf(a0v, __builtin_amdgcn_sinf(__builtin_amdgcn_fractf(p)), acc[16 + j]);
      }
    }
  }

  // ---- write-out ----
  if (ATOMIC) {
    float* outb = dst + (long long)b * T_OUT;
    if (k < FRAMES - 1) {
      const int t0 = 32 * k + 16;
      #pragma unroll
      for (int j = 0; j < 32; ++j) atomicAdd(outb + t0 + j, acc[j]);
    } else {
      #pragma unroll
      for (int j = 0; j < 16; ++j) atomicAdd(outb + 8176 + j, acc[j]);
      #pragma unroll
      for (int j = 0; j < 16; ++j) atomicAdd(outb + j, acc[16 + j]);
    }
  } else {
    float* pout = dst + (long long)(b * NCT + chunk) * T_OUT;
    if (k < FRAMES - 1) {
      const int t0 = 32 * k + 16;
      #pragma unroll
      for (int j = 0; j < 8; ++j) {
        reinterpret_cast<float4*>(pout + t0)[j] =
            make_float4(acc[4*j], acc[4*j+1], acc[4*j+2], acc[4*j+3]);
      }
    } else {
      #pragma unroll
      for (int j = 0; j < 4; ++j)
        reinterpret_cast<float4*>(pout + 8176)[j] =
            make_float4(acc[4*j], acc[4*j+1], acc[4*j+2], acc[4*j+3]);
      #pragma unroll
      for (int j = 0; j < 4; ++j)
        reinterpret_cast<float4*>(pout)[j] =
            make_float4(acc[16+4*j], acc[17+4*j], acc[18+4*j], acc[19+4*j]);
    }
  }
}

__global__ __launch_bounds__(256) void reduce_out(
    const float* __restrict__ partial, float* __restrict__ out, int nc)
{
  const int i = blockIdx.x * 256 + threadIdx.x;   // 0..32767
  const int b = i >> 13;
  const int t = i & (T_OUT - 1);
  const float* p = partial + (long long)(b * nc) * T_OUT + t;
  float s = 0.f;
  #pragma unroll 10
  for (int c = 0; c < nc; ++c) s += p[(long long)c * T_OUT];
  out[i] = s;
}

extern "C" void kernel_launch(void* const* d_in, const int* in_sizes, int n_in,
                              void* d_out, int out_size, void* d_ws, size_t ws_size,
                              hipStream_t stream) {
  const float* freq  = (const float*)d_in[0];
  const float* amp   = (const float*)d_in[1];
  const float* initp = (const float*)d_in[2];
  float* out = (float*)d_out;

  constexpr int CH_A = 4,  NC_A = 250;   // preferred: 1000 blocks, 32.8 MB ws
  constexpr int CH_B = 8,  NC_B = 125;   // fallback:  500 blocks, 16.4 MB ws
  const size_t need_a = (size_t)BATCH * NC_A * T_OUT * sizeof(float);
  const size_t need_b = (size_t)BATCH * NC_B * T_OUT * sizeof(float);

  if (ws_size >= need_a) {
    float* partial = (float*)d_ws;
    synth_partial<CH_A, NC_A, false><<<dim3(BATCH * NC_A), dim3(256), 0, stream>>>(
        freq, amp, initp, partial);
    reduce_out<<<dim3((BATCH * T_OUT) / 256), dim3(256), 0, stream>>>(
        partial, out, NC_A);
  } else if (ws_size >= need_b) {
    float* partial = (float*)d_ws;
    synth_partial<CH_B, NC_B, false><<<dim3(BATCH * NC_B), dim3(256), 0, stream>>>(
        freq, amp, initp, partial);
    reduce_out<<<dim3((BATCH * T_OUT) / 256), dim3(256), 0, stream>>>(
        partial, out, NC_B);
  } else {
    // last-resort: accumulate directly into out with atomics
    hipMemsetAsync(d_out, 0, (size_t)out_size * sizeof(float), stream);
    synth_partial<CH_B, NC_B, true><<<dim3(BATCH * NC_B), dim3(256), 0, stream>>>(
        freq, amp, initp, out);
  }
}

// Round 3
// 25.295 us; speedup vs baseline: 1.8176x; 1.8176x over previous
//
#include <hip/hip_runtime.h>

// SineSynth: B=4, S=1000 sines, F=256 frames, 32x linear upsample -> T=8192.
// out[b][t] = sum_s amp_up[b,s,t] * sin( cumsum(freq_up*2pi/FS)[t] + init[b,s] )
//
// Closed-form phase (REVOLUTIONS -> v_fract feeds v_sin_f32):
//   t = 32k+16+j:  base(k) = 16*(C[k]+C[k+1])/FS + init/2pi,  C[k]=sum_{m<k} f[m]
//   p(j) = base + c1*(j+1) + c2*(j+1)^2,  c1=f[k]/FS, c2=(f[k+1]-f[k])/(64 FS)
//   am(j) = a[k] + (a[k+1]-a[k])*(j+0.5)/32 = fma(d1, j+1, a0')  a0'=a[k]-d1/2
//   head t<16: p=(t+1)f[0]/FS+init/2pi, am=a[0]  (regular form, kA=kA1=0, bs=headfrac)
//   tail k=255: kA=kA1=255 => c2=d1=0  (regular form exactly)
//
// Thread decomposition: 2000 blocks = 4b x 125chunk x 4kq; thread owns ONE
// quarter-segment (8 samples) of ONE k for 8 sines => acc[8], ~50 VGPR,
// 8 waves/SIMD fully resident. Special (k==255) threads remapped branch-free.

#define FS_D 44100.0
#define S_TOTAL 1000
#define FRAMES 256
#define T_OUT 8192
#define BATCH 4
#define CH 8
#define NC 125      // CH*NC = S_TOTAL
#define KQ 4

template <bool ATOMIC>
__global__ __launch_bounds__(256) void synth(
    const float* __restrict__ freq, const float* __restrict__ amp,
    const float* __restrict__ initp, float* __restrict__ dst)
{
  __shared__ float base_lds[CH][FRAMES];
  __shared__ float head_lds[CH];

  const int bx    = blockIdx.x;
  const int b     = bx / (NC * KQ);
  const int rem   = bx % (NC * KQ);
  const int chunk = rem >> 2;
  const int kq    = rem & 3;
  const int s0    = chunk * CH;
  const int tid   = threadIdx.x;
  const int lane  = tid & 63;
  const int wave  = tid >> 6;

  const double inv2pi = 0.15915494309189535;
  const double k16    = 16.0 / FS_D;

  // ---- Phase 1: per-row exclusive scan (double) -> segment base fracs ----
  #pragma unroll
  for (int r = wave; r < CH; r += 4) {
    const int s = s0 + r;
    const long long roff = (long long)(b * S_TOTAL + s) * FRAMES;
    const float4 fv = reinterpret_cast<const float4*>(freq + roff)[lane];
    const double f0 = fv.x, f1 = fv.y, f2 = fv.z, f3 = fv.w;
    const double tot = f0 + f1 + f2 + f3;
    double incl = tot;
    #pragma unroll
    for (int off = 1; off < 64; off <<= 1) {
      double v = __shfl_up(incl, (unsigned)off, 64);
      if (lane >= off) incl += v;
    }
    double C = incl - tot;  // exclusive prefix of frames at 4*lane
    const double initrev = (double)initp[b * S_TOTAL + s] * inv2pi;
    if (lane == 0) head_lds[r] = (float)(initrev - floor(initrev));
    const double fk[4] = {f0, f1, f2, f3};
    #pragma unroll
    for (int i = 0; i < 4; ++i) {
      const double basev = k16 * (2.0 * C + fk[i]) + initrev;
      base_lds[r][4 * lane + i] = (float)(basev - floor(basev));
      C += fk[i];
    }
  }
  __syncthreads();

  // ---- Phase 2: thread = (k-group g, quarter q); 8 samples, 8 sines ----
  const int g = tid >> 2;            // 0..63
  const int q = tid & 3;             // 0..3
  const int k = kq * 64 + g;         // 0..255
  const bool special = (k == 255);   // tail (q<2) + head (q>=2)
  const bool hd      = special && (q >= 2);
  const int kA  = hd ? 0 : k;
  const int kA1 = special ? kA : (kA + 1);
  const int qq  = hd ? (q - 2) : q;
  const int j0  = qq * 8;
  const int t0  = hd ? j0 : (kA * 32 + 16 + j0);

  float uu[8], u2[8];
  const float u0f = (float)(j0 + 1);
  #pragma unroll
  for (int jj = 0; jj < 8; ++jj) {
    uu[jj] = u0f + (float)jj;
    u2[jj] = uu[jj] * uu[jj];
  }

  float acc[8];
  #pragma unroll
  for (int jj = 0; jj < 8; ++jj) acc[jj] = 0.f;

  const float invfs = (float)(1.0 / FS_D);

  #pragma unroll
  for (int r = 0; r < CH; ++r) {
    const long long roff = (long long)(b * S_TOTAL + s0 + r) * FRAMES;
    const float fA  = freq[roff + kA];
    const float fA1 = freq[roff + kA1];
    const float aA  = amp[roff + kA];
    const float aA1 = amp[roff + kA1];
    const float bs  = hd ? head_lds[r] : base_lds[r][kA];
    const float c1  = fA * invfs;
    const float c2  = (fA1 - fA) * (invfs * (1.0f / 64.0f));
    const float d1  = (aA1 - aA) * (1.0f / 32.0f);
    const float a0p = fmaf(-0.5f, d1, aA);
    #pragma unroll
    for (int jj = 0; jj < 8; ++jj) {
      const float p  = fmaf(c2, u2[jj], fmaf(c1, uu[jj], bs));
      const float am = fmaf(d1, uu[jj], a0p);
      acc[jj] = fmaf(am, __builtin_amdgcn_sinf(__builtin_amdgcn_fractf(p)), acc[jj]);
    }
  }

  // ---- write-out: 8 contiguous floats at t0 (32B-aligned) ----
  if (ATOMIC) {
    float* outb = dst + (long long)b * T_OUT + t0;
    #pragma unroll
    for (int jj = 0; jj < 8; ++jj) atomicAdd(outb + jj, acc[jj]);
  } else {
    float* pout = dst + (long long)(b * NC + chunk) * T_OUT + t0;
    reinterpret_cast<float4*>(pout)[0] = make_float4(acc[0], acc[1], acc[2], acc[3]);
    reinterpret_cast<float4*>(pout)[1] = make_float4(acc[4], acc[5], acc[6], acc[7]);
  }
}

__global__ __launch_bounds__(256) void reduce_out(
    const float* __restrict__ partial, float* __restrict__ out)
{
  __shared__ float red[4][64];
  const int tid  = threadIdx.x;
  const int lane = tid & 63;
  const int w    = tid >> 6;
  const int i    = blockIdx.x * 64 + lane;    // 0..32767
  const int b    = i >> 13;
  const int t    = i & (T_OUT - 1);
  const float* p = partial + (long long)b * NC * T_OUT + t;
  float s = 0.f;
  #pragma unroll 8
  for (int c = w; c < NC; c += 4) s += p[(long long)c * T_OUT];
  red[w][lane] = s;
  __syncthreads();
  if (tid < 64) {
    out[i] = (red[0][lane] + red[1][lane]) + (red[2][lane] + red[3][lane]);
  }
}

extern "C" void kernel_launch(void* const* d_in, const int* in_sizes, int n_in,
                              void* d_out, int out_size, void* d_ws, size_t ws_size,
                              hipStream_t stream) {
  const float* freq  = (const float*)d_in[0];
  const float* amp   = (const float*)d_in[1];
  const float* initp = (const float*)d_in[2];
  float* out = (float*)d_out;

  const size_t need = (size_t)BATCH * NC * T_OUT * sizeof(float);  // 16.4 MB

  if (ws_size >= need) {
    float* partial = (float*)d_ws;
    synth<false><<<dim3(BATCH * NC * KQ), dim3(256), 0, stream>>>(
        freq, amp, initp, partial);
    reduce_out<<<dim3((BATCH * T_OUT) / 64), dim3(256), 0, stream>>>(
        partial, out);
  } else {
    hipMemsetAsync(d_out, 0, (size_t)out_size * sizeof(float), stream);
    synth<true><<<dim3(BATCH * NC * KQ), dim3(256), 0, stream>>>(
        freq, amp, initp, out);
  }
}

// Round 4
// 22.318 us; speedup vs baseline: 2.0601x; 1.1334x over previous
//
#include <hip/hip_runtime.h>
#include <hip/hip_fp16.h>

// SineSynth: B=4, S=1000 sines, F=256 frames, 32x linear upsample -> T=8192.
// out[b][t] = sum_s amp_up[b,s,t] * sin( cumsum(freq_up*2pi/FS)[t] + init[b,s] )
//
// Closed-form phase (REVOLUTIONS -> v_fract feeds v_sin_f32):
//   t = 32k+16+j:  base(k) = 16*(C[k]+C[k+1])/FS + init/2pi,  C[k]=sum_{m<k} f[m]
//   p(j) = base + c1*(j+1) + c2*(j+1)^2,  c1=f[k]/FS, c2=(f[k+1]-f[k])/(64 FS)
//   am(j) = fma(d1, j+1, a0'),  d1=(a[k+1]-a[k])/32, a0'=a[k]-d1/2
//   head t<16: p=(t+1)f[0]/FS+init/2pi, am=a[0];  tail k=255: c2=d1=0
//
// Decomposition: 2000 blocks = 4b x 125chunk x 4kq; lane = k-offset (64
// consecutive k per block -> coalesced loads), wave = quarter (8 samples).
// Coefs staged once per (r,k) in LDS; partials stored fp16.

#define FS_D 44100.0
#define S_TOTAL 1000
#define FRAMES 256
#define T_OUT 8192
#define BATCH 4
#define CH 8
#define NC 125      // CH*NC = S_TOTAL
#define KQ 4

template <bool ATOMIC>
__global__ __launch_bounds__(256, 8) void synth(
    const float* __restrict__ freq, const float* __restrict__ amp,
    const float* __restrict__ initp, __half* __restrict__ pdst,
    float* __restrict__ odst)
{
  __shared__ float base_lds[CH][FRAMES];
  __shared__ float head_lds[CH];
  __shared__ float4 coef_lds[CH][64];   // (c1, c2, d1, a0p) per (r, k-local)

  const int bx    = blockIdx.x;
  const int b     = bx / (NC * KQ);
  const int rem   = bx % (NC * KQ);
  const int chunk = rem >> 2;
  const int kq    = rem & 3;
  const int s0    = chunk * CH;
  const int tid   = threadIdx.x;
  const int lane  = tid & 63;
  const int wave  = tid >> 6;

  const float invfs = (float)(1.0 / FS_D);

  // ---- Phase 2a: stage coefficients, one (r,k) set computed ONCE ----
  {
    const int kA  = kq * 64 + lane;
    const int kA1 = (kA < FRAMES - 1) ? kA + 1 : kA;   // tail: c2=d1=0
    #pragma unroll
    for (int i = 0; i < 2; ++i) {
      const int r = 2 * wave + i;
      const long long roff = (long long)(b * S_TOTAL + s0 + r) * FRAMES;
      const float fA  = freq[roff + kA];
      const float fA1 = freq[roff + kA1];
      const float aA  = amp[roff + kA];
      const float aA1 = amp[roff + kA1];
      const float c1  = fA * invfs;
      const float c2  = (fA1 - fA) * (invfs * (1.0f / 64.0f));
      const float d1  = (aA1 - aA) * (1.0f / 32.0f);
      const float a0p = fmaf(-0.5f, d1, aA);
      coef_lds[r][lane] = make_float4(c1, c2, d1, a0p);
    }
  }

  // ---- Phase 1: per-row exclusive scan (double) -> segment base fracs ----
  {
    const double inv2pi = 0.15915494309189535;
    const double k16    = 16.0 / FS_D;
    #pragma unroll
    for (int r = wave; r < CH; r += 4) {
      const int s = s0 + r;
      const long long roff = (long long)(b * S_TOTAL + s) * FRAMES;
      const float4 fv = reinterpret_cast<const float4*>(freq + roff)[lane];
      const double f0 = fv.x, f1 = fv.y, f2 = fv.z, f3 = fv.w;
      const double tot = f0 + f1 + f2 + f3;
      double incl = tot;
      #pragma unroll
      for (int off = 1; off < 64; off <<= 1) {
        double v = __shfl_up(incl, (unsigned)off, 64);
        if (lane >= off) incl += v;
      }
      double C = incl - tot;  // exclusive prefix of frames at 4*lane
      const double initrev = (double)initp[b * S_TOTAL + s] * inv2pi;
      if (lane == 0) head_lds[r] = (float)(initrev - floor(initrev));
      const double fk[4] = {f0, f1, f2, f3};
      #pragma unroll
      for (int i = 0; i < 4; ++i) {
        const double basev = k16 * (2.0 * C + fk[i]) + initrev;
        base_lds[r][4 * lane + i] = (float)(basev - floor(basev));
        C += fk[i];
      }
    }
  }
  __syncthreads();

  // ---- Phase 2b: thread = (k = kq*64+lane, quarter q = wave) ----
  const int q = wave;                 // 0..3
  const int k = kq * 64 + lane;       // 0..255
  const bool special = (k == FRAMES - 1);
  const bool hd      = special && (q >= 2);   // head t=0..15
  const int qq  = hd ? (q - 2) : q;
  const int j0  = qq * 8;
  const int t0  = hd ? j0 : (k * 32 + 16 + j0);

  float uu[8];
  const float u0f = (float)(j0 + 1);
  #pragma unroll
  for (int jj = 0; jj < 8; ++jj) uu[jj] = u0f + (float)jj;

  float acc[8];
  #pragma unroll
  for (int jj = 0; jj < 8; ++jj) acc[jj] = 0.f;

  #pragma unroll
  for (int r = 0; r < CH; ++r) {
    float4 cf = coef_lds[r][lane];
    float bs  = base_lds[r][k];
    if (hd) {   // one lane in waves 2,3 of kq==3 blocks only
      const long long roff0 = (long long)(b * S_TOTAL + s0 + r) * FRAMES;
      cf.x = freq[roff0] * invfs;  // c1 = f0/FS
      cf.y = 0.f; cf.z = 0.f;
      cf.w = amp[roff0];           // a0p = a0 (d1 = 0)
      bs   = head_lds[r];
    }
    #pragma unroll
    for (int jj = 0; jj < 8; ++jj) {
      const float p  = fmaf(fmaf(cf.y, uu[jj], cf.x), uu[jj], bs);
      const float am = fmaf(cf.z, uu[jj], cf.w);
      acc[jj] = fmaf(am, __builtin_amdgcn_sinf(__builtin_amdgcn_fractf(p)), acc[jj]);
    }
  }

  // ---- write-out ----
  if (ATOMIC) {
    float* outb = odst + (long long)b * T_OUT + t0;
    #pragma unroll
    for (int jj = 0; jj < 8; ++jj) atomicAdd(outb + jj, acc[jj]);
  } else {
    __half* pout = pdst + (size_t)(b * NC + chunk) * T_OUT + t0;
    union { float4 f; __half2 h[4]; } u;
    u.h[0] = __floats2half2_rn(acc[0], acc[1]);
    u.h[1] = __floats2half2_rn(acc[2], acc[3]);
    u.h[2] = __floats2half2_rn(acc[4], acc[5]);
    u.h[3] = __floats2half2_rn(acc[6], acc[7]);
    *reinterpret_cast<float4*>(pout) = u.f;
  }
}

__global__ __launch_bounds__(256) void reduce_out(
    const __half* __restrict__ partial, float* __restrict__ out)
{
  __shared__ float red_x[4][64];
  __shared__ float red_y[4][64];
  const int tid  = threadIdx.x;
  const int lane = tid & 63;
  const int w    = tid >> 6;
  const int i    = blockIdx.x * 64 + lane;    // half2 index, 0..16383
  const int b    = i >> 12;                   // 4096 half2 per batch
  const int t2   = i & 4095;
  const __half2* p =
      reinterpret_cast<const __half2*>(partial + (size_t)b * NC * T_OUT) + t2;
  float sx = 0.f, sy = 0.f;
  #pragma unroll 8
  for (int c = w; c < NC; c += 4) {
    const float2 v = __half22float2(p[c * (T_OUT / 2)]);
    sx += v.x; sy += v.y;
  }
  red_x[w][lane] = sx;
  red_y[w][lane] = sy;
  __syncthreads();
  if (tid < 64) {
    const float ox = (red_x[0][lane] + red_x[1][lane]) +
                     (red_x[2][lane] + red_x[3][lane]);
    const float oy = (red_y[0][lane] + red_y[1][lane]) +
                     (red_y[2][lane] + red_y[3][lane]);
    reinterpret_cast<float2*>(out)[i] = make_float2(ox, oy);
  }
}

extern "C" void kernel_launch(void* const* d_in, const int* in_sizes, int n_in,
                              void* d_out, int out_size, void* d_ws, size_t ws_size,
                              hipStream_t stream) {
  const float* freq  = (const float*)d_in[0];
  const float* amp   = (const float*)d_in[1];
  const float* initp = (const float*)d_in[2];
  float* out = (float*)d_out;

  const size_t need = (size_t)BATCH * NC * T_OUT * sizeof(__half);  // 8.2 MB

  if (ws_size >= need) {
    __half* partial = (__half*)d_ws;
    synth<false><<<dim3(BATCH * NC * KQ), dim3(256), 0, stream>>>(
        freq, amp, initp, partial, nullptr);
    reduce_out<<<dim3((BATCH * T_OUT / 2) / 64), dim3(256), 0, stream>>>(
        partial, out);
  } else {
    hipMemsetAsync(d_out, 0, (size_t)out_size * sizeof(float), stream);
    synth<true><<<dim3(BATCH * NC * KQ), dim3(256), 0, stream>>>(
        freq, amp, initp, nullptr, out);
  }
}

// Round 5
// 21.627 us; speedup vs baseline: 2.1259x; 1.0320x over previous
//
#include <hip/hip_runtime.h>
#include <hip/hip_fp16.h>

// SineSynth: B=4, S=1000 sines, F=256 frames, 32x linear upsample -> T=8192.
// out[b][t] = sum_s amp_up[b,s,t] * sin( cumsum(freq_up*2pi/FS)[t] + init[b,s] )
//
// Closed-form phase (REVOLUTIONS -> v_fract feeds v_sin_f32):
//   t = 32k+16+j:  base(k) = 16*(C[k]+C[k+1])/FS + init/2pi,  C[k]=sum_{m<k} f[m]
//   p(j) = base + c1*(j+1) + c2*(j+1)^2,  c1=f[k]/FS, c2=(f[k+1]-f[k])/(64 FS)
//   am(j) = fma(d1, j+1, a0'),  d1=(a[k+1]-a[k])/32, a0'=a[k]-d1/2
//   head t<16: p=(t+1)f[0]/FS+init/2pi, am=a[0]  -> virtual coef column 256
//   tail k=255: kA1=kA => c2=d1=0 (regular form)
//
// One 1024-thread block per (b,chunk): phase1 scan + coef staging done ONCE
// (was 4x redundant across kq blocks). 500 blocks x 16 waves, 2 blocks/CU,
// 8 waves/SIMD. Thread (w,lane): k=(w>>2)*64+lane, quarter q=w&3 (8 samples).

#define FS_D 44100.0
#define S_TOTAL 1000
#define FRAMES 256
#define T_OUT 8192
#define BATCH 4
#define CH 8
#define NC 125      // CH*NC = S_TOTAL

template <bool ATOMIC>
__global__ __launch_bounds__(1024, 8) void synth(
    const float* __restrict__ freq, const float* __restrict__ amp,
    const float* __restrict__ initp, __half* __restrict__ pdst,
    float* __restrict__ odst)
{
  __shared__ float4 coef_lds[CH][FRAMES + 1];  // (c1,c2,d1,a0p); col 256 = head
  __shared__ float  base_lds[CH][FRAMES + 4];  // 260: pad for b128 writes; col 256 = head frac

  const int bx    = blockIdx.x;
  const int b     = bx / NC;
  const int chunk = bx % NC;
  const int s0    = chunk * CH;
  const int tid   = threadIdx.x;
  const int lane  = tid & 63;
  const int w     = tid >> 6;      // 0..15

  const float invfs = (float)(1.0 / FS_D);

  // ---- Phase 2a: stage coefficients (16 waves x 2 sweeps = 8 rows x 256 k) ----
  #pragma unroll
  for (int rr = 0; rr < 2; ++rr) {
    const int r  = rr * 4 + (w >> 2);
    const int kA = (w & 3) * 64 + lane;
    const int kA1 = (kA < FRAMES - 1) ? kA + 1 : kA;   // tail clamp: c2=d1=0
    const long long roff = (long long)(b * S_TOTAL + s0 + r) * FRAMES;
    const float fA  = freq[roff + kA];
    const float fA1 = freq[roff + kA1];
    const float aA  = amp[roff + kA];
    const float aA1 = amp[roff + kA1];
    const float c1  = fA * invfs;
    const float c2  = (fA1 - fA) * (invfs * (1.0f / 64.0f));
    const float d1  = (aA1 - aA) * (1.0f / 32.0f);
    const float a0p = fmaf(-0.5f, d1, aA);
    coef_lds[r][kA] = make_float4(c1, c2, d1, a0p);
    if (kA == 0) coef_lds[r][FRAMES] = make_float4(c1, 0.f, 0.f, aA);  // head
  }

  // ---- Phase 1: per-row exclusive scan (double), waves 0..7, one row each ----
  if (w < 8) {
    const int r = w;
    const double inv2pi = 0.15915494309189535;
    const double k16    = 16.0 / FS_D;
    const long long roff = (long long)(b * S_TOTAL + s0 + r) * FRAMES;
    const float4 fv = reinterpret_cast<const float4*>(freq + roff)[lane];
    const double f0 = fv.x, f1 = fv.y, f2 = fv.z, f3 = fv.w;
    const double tot = f0 + f1 + f2 + f3;
    double incl = tot;
    #pragma unroll
    for (int off = 1; off < 64; off <<= 1) {
      double v = __shfl_up(incl, (unsigned)off, 64);
      if (lane >= off) incl += v;
    }
    double C = incl - tot;  // exclusive prefix of frames at 4*lane
    const double initrev = (double)initp[b * S_TOTAL + s0 + r] * inv2pi;
    if (lane == 0) base_lds[r][FRAMES] = (float)(initrev - floor(initrev));
    const double fk[4] = {f0, f1, f2, f3};
    float4 bw;
    #pragma unroll
    for (int i = 0; i < 4; ++i) {
      const double basev = k16 * (2.0 * C + fk[i]) + initrev;
      (&bw.x)[i] = (float)(basev - floor(basev));
      C += fk[i];
    }
    *reinterpret_cast<float4*>(&base_lds[r][4 * lane]) = bw;  // aligned b128
  }
  __syncthreads();

  // ---- Phase 2b: thread = (k=(w>>2)*64+lane, quarter q=w&3), 8 samples ----
  const int q = w & 3;
  const int k = (w >> 2) * 64 + lane;      // 0..255
  const bool hd = (k == FRAMES - 1) && (q >= 2);   // head t=0..15
  const int kidx = hd ? FRAMES : k;
  const int qq = hd ? (q - 2) : q;
  const int j0 = qq * 8;
  const int t0 = hd ? j0 : (k * 32 + 16 + j0);

  float uu[8];
  const float u0f = (float)(j0 + 1);
  #pragma unroll
  for (int jj = 0; jj < 8; ++jj) uu[jj] = u0f + (float)jj;

  float acc[8];
  #pragma unroll
  for (int jj = 0; jj < 8; ++jj) acc[jj] = 0.f;

  #pragma unroll
  for (int r = 0; r < CH; ++r) {
    const float4 cf = coef_lds[r][kidx];
    const float  bs = base_lds[r][kidx];
    #pragma unroll
    for (int jj = 0; jj < 8; ++jj) {
      const float p  = fmaf(fmaf(cf.y, uu[jj], cf.x), uu[jj], bs);
      const float am = fmaf(cf.z, uu[jj], cf.w);
      acc[jj] = fmaf(am, __builtin_amdgcn_sinf(__builtin_amdgcn_fractf(p)), acc[jj]);
    }
  }

  // ---- write-out ----
  if (ATOMIC) {
    float* outb = odst + (long long)b * T_OUT + t0;
    #pragma unroll
    for (int jj = 0; jj < 8; ++jj) atomicAdd(outb + jj, acc[jj]);
  } else {
    __half* pout = pdst + (size_t)(b * NC + chunk) * T_OUT + t0;
    union { float4 f; __half2 h[4]; } u;
    u.h[0] = __floats2half2_rn(acc[0], acc[1]);
    u.h[1] = __floats2half2_rn(acc[2], acc[3]);
    u.h[2] = __floats2half2_rn(acc[4], acc[5]);
    u.h[3] = __floats2half2_rn(acc[6], acc[7]);
    *reinterpret_cast<float4*>(pout) = u.f;
  }
}

__global__ __launch_bounds__(256) void reduce_out(
    const __half* __restrict__ partial, float* __restrict__ out)
{
  __shared__ float red_x[4][64];
  __shared__ float red_y[4][64];
  const int tid  = threadIdx.x;
  const int lane = tid & 63;
  const int w    = tid >> 6;
  const int i    = blockIdx.x * 64 + lane;    // half2 index, 0..16383
  const int b    = i >> 12;                   // 4096 half2 per batch
  const int t2   = i & 4095;
  const __half2* p =
      reinterpret_cast<const __half2*>(partial + (size_t)b * NC * T_OUT) + t2;
  float sx = 0.f, sy = 0.f;
  #pragma unroll 8
  for (int c = w; c < NC; c += 4) {
    const float2 v = __half22float2(p[c * (T_OUT / 2)]);
    sx += v.x; sy += v.y;
  }
  red_x[w][lane] = sx;
  red_y[w][lane] = sy;
  __syncthreads();
  if (tid < 64) {
    const float ox = (red_x[0][lane] + red_x[1][lane]) +
                     (red_x[2][lane] + red_x[3][lane]);
    const float oy = (red_y[0][lane] + red_y[1][lane]) +
                     (red_y[2][lane] + red_y[3][lane]);
    reinterpret_cast<float2*>(out)[i] = make_float2(ox, oy);
  }
}

extern "C" void kernel_launch(void* const* d_in, const int* in_sizes, int n_in,
                              void* d_out, int out_size, void* d_ws, size_t ws_size,
                              hipStream_t stream) {
  const float* freq  = (const float*)d_in[0];
  const float* amp   = (const float*)d_in[1];
  const float* initp = (const float*)d_in[2];
  float* out = (float*)d_out;

  const size_t need = (size_t)BATCH * NC * T_OUT * sizeof(__half);  // 8.2 MB

  if (ws_size >= need) {
    __half* partial = (__half*)d_ws;
    synth<false><<<dim3(BATCH * NC), dim3(1024), 0, stream>>>(
        freq, amp, initp, partial, nullptr);
    reduce_out<<<dim3((BATCH * T_OUT / 2) / 64), dim3(256), 0, stream>>>(
        partial, out);
  } else {
    hipMemsetAsync(d_out, 0, (size_t)out_size * sizeof(float), stream);
    synth<true><<<dim3(BATCH * NC), dim3(1024), 0, stream>>>(
        freq, amp, initp, nullptr, out);
  }
}